// Round 5
// baseline (155.882 us; speedup 1.0000x reference)
//
#include <hip/hip_runtime.h>
#include <math.h>

#define DIMS 160
#define PLANE (DIMS*DIMS)          // 25600
#define NB 2
#define RH 7
#define RL 4
#define KH 15
#define KL 9
#define TSX 16
#define TSY 32
#define NTX (DIMS/TSX)             // 10
#define NTY (DIMS/TSY)             // 5
#define CZ 32                      // best measured halo amortization (v9)
#define NCH (DIMS/CZ)              // 5
#define NSTEPS (CZ + 2*RH)         // 46 planes marched (even -> clean 2-seg pairing)
#define YHR (TSY + 2*RH)           // 46 conv rows
// sX bank geometry (v9-proven): b64 read at cx*S with gcd(S mod 32,32)==2 ->
// 16 distinct even start banks, word-pairs tile all 32 banks. Scalar xconv
// writes: exactly 2-way (free, m136).
#define SH 50                      // sXh col stride
#define SL 42                      // sXl col stride
#define XHSZ (TSX*SH)              // 800
#define XLSZ (TSX*SL)              // 672
#define NTHREADS 448               // 7 waves: yconv w0-3, xconv w4-6 (+8 idle lanes)
#define NBLK (NTX*NTY*NCH*NB)      // 500 blocks

struct DoGW { float gl[KL]; float gh[KH]; };

// v12: delete sRaw staging. v11 post-mortem: occupancy pinned ~32% across all
// VGPR/grid configs -> latency-bound on the per-segment critical path, and the
// global->LDS->xconv staging is a whole stage of that path spent sharing data
// that is L2-resident anyway (x-halo re-reads are 2.5x unique bytes, all L2).
// xconv now loads its 20-float window straight from global (5x float4,
// 16B-aligned), distance-1 ping-pong register prefetch (PA/PB, static index),
// issued at segment start so the in-flight window ~= the full segment before
// the barrier's vmcnt drain (same slack v9's loader had). Removes the loader
// role, 17.3KB LDS, ~20 DS-insts/step, and one barrier-to-barrier stage.
// yconv (2 cols, b64, merged DoG ring) and sX dbuf unchanged from v9/v11.
__global__ __launch_bounds__(NTHREADS, 4)
void dog_v12(const float* __restrict__ X, float* __restrict__ out, DoGW w) {
  __shared__ __align__(16) float sXh[2][XHSZ];     // 6.25 KB
  __shared__ __align__(16) float sXl[2][XLSZ];     // 5.25 KB  (11.5 KB total)

  const int bid = blockIdx.x;
  const int xt = bid % NTX;
  const int yt = (bid / NTX) % NTY;
  const int zc = (bid / (NTX * NTY)) % NCH;
  const int b  = bid / (NTX * NTY * NCH);
  const int x0 = xt * TSX, y0 = yt * TSY, z0 = zc * CZ;
  const float* Xb = X + (size_t)b * DIMS * PLANE;
  const int tid = threadIdx.x;

  // ---- yconv role: threads 0..255 (w0-3), 2 adjacent y columns each ----
  const bool y_on = tid < 256;
  const int cx  = tid & 15;
  const int cy0 = 2 * ((tid >> 4) & 15);           // even -> 8B-aligned b64 windows
  const int hb = cx * SH + cy0;
  const int lb = cx * SL + cy0;
  float* const obase = out + ((size_t)b * DIMS * PLANE) + (size_t)(y0 + cy0) * DIMS + (x0 + cx);

  // ---- xconv role: threads 256..439 (w4-6; 184 = 46 rows x 4 quads) ----
  const bool x_on = (tid >= 256) && (tid < 256 + YHR * 4);
  const int xu = tid - 256;
  const int xr = xu >> 2, xq = xu & 3;
  const int xyg = min(max(y0 + xr - RH, 0), DIMS - 1);   // replicate y-clamp
  const int gx0 = x0 - 8 + 4 * xq;                 // window global x start (16B-aligned)
  const bool tfast = (gx0 >= 0) && (gx0 + 20 <= DIMS);

  // distance-1 ping-pong prefetch sets (named, statically indexed - rule #20)
  float4 PA[5], PB[5];

  auto issueLoad = [&](int s, float4 (&P)[5]) {
    const int zsrc = min(max(z0 - RH + s, 0), DIMS - 1);
    const float* rp = Xb + ((size_t)zsrc * DIMS + xyg) * DIMS;
    if (tfast) {
      #pragma unroll
      for (int j = 0; j < 5; ++j) P[j] = *(const float4*)(rp + gx0 + 4 * j);
    } else {                                        // edge tiles: replicate x-clamp
      #pragma unroll
      for (int j = 0; j < 5; ++j) {
        P[j].x = rp[min(max(gx0 + 4 * j + 0, 0), DIMS - 1)];
        P[j].y = rp[min(max(gx0 + 4 * j + 1, 0), DIMS - 1)];
        P[j].z = rp[min(max(gx0 + 4 * j + 2, 0), DIMS - 1)];
        P[j].w = rp[min(max(gx0 + 4 * j + 3, 0), DIMS - 1)];
      }
    }
  };

  auto xcompute = [&](int cur, const float4 (&P)[5]) {
    float v[20];                                   // static extraction -> SSA, no movs
    #pragma unroll
    for (int j = 0; j < 5; ++j) {
      v[4 * j] = P[j].x; v[4 * j + 1] = P[j].y; v[4 * j + 2] = P[j].z; v[4 * j + 3] = P[j].w;
    }
    #pragma unroll
    for (int c = 0; c < 4; ++c) {                  // high, K=15
      float a = 0.f;
      #pragma unroll
      for (int k = 0; k < KH; ++k) a = fmaf(w.gh[k], v[c + 1 + k], a);
      sXh[cur][(4 * xq + c) * SH + xr] = a;        // scalar write: exactly 2-way = free
    }
    if (xr >= 3 && xr <= 42) {
      #pragma unroll
      for (int c = 0; c < 4; ++c) {                // low, K=9
        float a = 0.f;
        #pragma unroll
        for (int k = 0; k < KL; ++k) a = fmaf(w.gl[k], v[c + 4 + k], a);
        sXl[cur][(4 * xq + c) * SL + (xr - 3)] = a;
      }
    }
  };

  // merged DoG z-rings (v11-proven): D[i] += gl-part - gh-part; retire D[0].
  float D0[KH], D1[KH];
  #pragma unroll
  for (int i = 0; i < KH; ++i) { D0[i] = 0.f; D1[i] = 0.f; }

  auto consumeQ = [&](int q) {
    const int qb = q & 1;
    float f[16], g[10];
    #pragma unroll
    for (int j = 0; j < 8; ++j) {                  // ds_read_b64: conflict-free geometry
      float2 t = *(const float2*)&sXh[qb][hb + 2 * j];
      f[2 * j] = t.x; f[2 * j + 1] = t.y;
    }
    #pragma unroll
    for (int j = 0; j < 5; ++j) {
      float2 t = *(const float2*)&sXl[qb][lb + 2 * j];
      g[2 * j] = t.x; g[2 * j + 1] = t.y;
    }
    float ph0 = 0.f, ph1 = 0.f, pl0 = 0.f, pl1 = 0.f;
    #pragma unroll
    for (int j = 0; j < KH; ++j) {
      ph0 = fmaf(w.gh[j], f[j], ph0);
      ph1 = fmaf(w.gh[j], f[j + 1], ph1);
    }
    #pragma unroll
    for (int j = 0; j < KL; ++j) {
      pl0 = fmaf(w.gl[j], g[j], pl0);
      pl1 = fmaf(w.gl[j], g[j + 1], pl1);
    }
    #pragma unroll
    for (int i = 0; i < KH; ++i) {                 // -gh via free VOP3 neg modifier
      D0[i] = fmaf(-w.gh[KH - 1 - i], ph0, D0[i]);
      D1[i] = fmaf(-w.gh[KH - 1 - i], ph1, D1[i]);
    }
    #pragma unroll
    for (int i = 3; i < KL + 3; ++i) {
      D0[i] = fmaf(w.gl[KL + 2 - i], pl0, D0[i]);
      D1[i] = fmaf(w.gl[KL + 2 - i], pl1, D1[i]);
    }
    if (q >= 2 * RH) {
      float* op = obase + (size_t)(z0 + q - 2 * RH) * PLANE;
      op[0]    = D0[0];
      op[DIMS] = D1[0];
    }
    #pragma unroll
    for (int i = 0; i < KH - 1; ++i) { D0[i] = D0[i + 1]; D1[i] = D1[i + 1]; }
    D0[KH - 1] = 0.f; D1[KH - 1] = 0.f;
  };

  // one segment: issue next plane's loads FIRST (max in-flight before the
  // barrier drain), then yconv(q=s-1), then xconv(s) from the arrived set.
  auto seg = [&](int s, const float4 (&Prd)[5], float4 (&Pwr)[5]) {
    if (x_on && s + 1 < NSTEPS) issueLoad(s + 1, Pwr);
    if (y_on && s >= 1) consumeQ(s - 1);
    if (x_on) xcompute(s & 1, Prd);
    __syncthreads();                               // B(s+1): sX[s&1] ready
  };

  // prologue: plane 0 in flight
  if (x_on) issueLoad(0, PA);

  for (int sp = 0; sp < NSTEPS; sp += 2) {         // 46 = 23 static pairs
    seg(sp,     PA, PB);
    seg(sp + 1, PB, PA);
  }
  if (y_on) consumeQ(NSTEPS - 1);                  // epilogue: final plane + last stores
}

extern "C" void kernel_launch(void* const* d_in, const int* in_sizes, int n_in,
                              void* d_out, int out_size, void* d_ws, size_t ws_size,
                              hipStream_t stream) {
  const float* X = (const float*)d_in[0];
  float* out = (float*)d_out;

  DoGW w;
  {
    double s = 0.0;
    for (int i = 0; i < KL; ++i) {
      double t = i - (KL - 1) / 2.0;
      double g = exp(-(t * t) / (2.0 * 1.0 * 1.0));
      w.gl[i] = (float)g; s += g;
    }
    for (int i = 0; i < KL; ++i) w.gl[i] = (float)((double)w.gl[i] / s);
    s = 0.0;
    for (int i = 0; i < KH; ++i) {
      double t = i - (KH - 1) / 2.0;
      double g = exp(-(t * t) / (2.0 * 1.6 * 1.6));
      w.gh[i] = (float)g; s += g;
    }
    for (int i = 0; i < KH; ++i) w.gh[i] = (float)((double)w.gh[i] / s);
  }

  dog_v12<<<NBLK, NTHREADS, 0, stream>>>(X, out, w);
}

// Round 6
// 129.577 us; speedup vs baseline: 1.2030x; 1.2030x over previous
//
#include <hip/hip_runtime.h>
#include <math.h>

#define DIMS 160
#define PLANE (DIMS*DIMS)          // 25600
#define NB 2
#define RH 7
#define RL 4
#define KH 15
#define KL 9
#define TSX 16
#define TSY 32
#define NTX (DIMS/TSX)             // 10
#define NTY (DIMS/TSY)             // 5
#define CZ 32                      // best measured halo amortization (v9)
#define NCH (DIMS/CZ)              // 5
#define NSTEPS (CZ + 2*RH)         // 46 planes marched
#define NSEG (NSTEPS/2)            // 23 two-plane segments -> 24 barriers (was 47)
#define YHR (TSY + 2*RH)           // 46 raw halo rows
// Bank geometry (v9-proven): b64 read at cx*S with gcd(S mod 32,32)==2 ->
// 16 distinct even start banks, pairs tile all 32 banks (S=50, S=42).
// b128 at xr*SR+4*xq with SR mod 32==16 -> each 8-lane/128B phase tiles all
// 32 banks. Scalar xconv writes: exactly 2-way (free, m136).
#define SR 48                      // sRaw row stride
#define SH 50                      // sXh col stride
#define SL 42                      // sXl col stride
#define RAWSZ (YHR*SR)             // 2208
#define XHSZ (TSX*SH)              // 800
#define XLSZ (TSX*SL)              // 672
#define NBLK (NTX*NTY*NCH*NB)      // 500 blocks

struct DoGW { float gl[KL]; float gh[KH]; };

// v13 = v9 with TWO planes per barrier segment. Session evidence v7-v12:
// occupancy pinned 23-35% regardless of VGPR/LDS/grid; no pipe >50%; v12
// showed the bound is the per-barrier latency tax (~1k cyc drain+ramp paid
// 47x). Fix: 2-plane segments pay it 24x; the two consumeQ chains inside a
// segment are independent -> 2x ILP on the 15-deep fma chains. All v9
// geometry, roles, distance-2 pipeline, merged D-ring kept; buffers become
// [dbuf][2 planes] (57.5 KB LDS, 2 blocks/CU = observed residency).
__global__ __launch_bounds__(512, 4)
void dog_v13(const float* __restrict__ X, float* __restrict__ out, DoGW w) {
  __shared__ __align__(16) float sRaw[2][2][RAWSZ]; // 35.3 KB
  __shared__ __align__(16) float sXh[2][2][XHSZ];   // 12.8 KB
  __shared__ __align__(16) float sXl[2][2][XLSZ];   // 10.75 KB (57.5 KB total)

  const int bid = blockIdx.x;
  const int xt = bid % NTX;
  const int yt = (bid / NTX) % NTY;
  const int zc = (bid / (NTX * NTY)) % NCH;
  const int b  = bid / (NTX * NTY * NCH);
  const int x0 = xt * TSX, y0 = yt * TSY, z0 = zc * CZ;
  const float* Xb = X + (size_t)b * DIMS * PLANE;
  const int tid = threadIdx.x;
  const bool xfast = (x0 >= 8) && (x0 + 24 <= DIMS);

  // ---- yconv role: threads 0..255, 2 adjacent y columns each ----
  const bool y_on = tid < 256;
  const int cx  = tid & 15;
  const int cy0 = 2 * ((tid >> 4) & 15);           // even -> 8B-aligned b64 windows
  const int hb = cx * SH + cy0;
  const int lb = cx * SL + cy0;
  float* const obase = out + ((size_t)b * DIMS * PLANE) + (size_t)(y0 + cy0) * DIMS + (x0 + cx);

  // ---- xconv role: threads 256..439 (184 = 46 rows x 4 quads) ----
  const bool x_on = (tid >= 256) && (tid < 256 + YHR * 4);
  const int xu = tid - 256;
  const int xr = xu >> 2, xq = xu & 3;

  // ---- loader role: threads 328..511 (184 = 46 rows x 4), 8 floats/plane ----
  const bool l_on = tid >= (512 - YHR * 4);
  const int lu = tid - (512 - YHR * 4);
  const int lrow = lu >> 2, lt = lu & 3;
  const int lyg = min(max(y0 + lrow - RH, 0), DIMS - 1);
  const int lxb = x0 - 8 + 4 * lt;

  float4 a0, b0, a1, b1;                           // TWO planes in flight (distance-2 segs)

  auto loadP = [&](int s, float4& vA, float4& vB) {
    const int zsrc = min(max(z0 - RH + s, 0), DIMS - 1);
    const float* rowp = Xb + ((size_t)zsrc * DIMS + lyg) * DIMS;
    if (xfast) {
      vA = *(const float4*)(rowp + lxb);
      vB = *(const float4*)(rowp + lxb + 16);
    } else {
      vA.x = rowp[min(max(lxb + 0, 0), DIMS - 1)];
      vA.y = rowp[min(max(lxb + 1, 0), DIMS - 1)];
      vA.z = rowp[min(max(lxb + 2, 0), DIMS - 1)];
      vA.w = rowp[min(max(lxb + 3, 0), DIMS - 1)];
      vB.x = rowp[min(max(lxb + 16, 0), DIMS - 1)];
      vB.y = rowp[min(max(lxb + 17, 0), DIMS - 1)];
      vB.z = rowp[min(max(lxb + 18, 0), DIMS - 1)];
      vB.w = rowp[min(max(lxb + 19, 0), DIMS - 1)];
    }
  };
  auto stageP = [&](int buf, int slot, const float4& vA, const float4& vB) {
    float* p = &sRaw[buf][slot][lrow * SR + 4 * lt];
    *(float4*)(p) = vA;
    *(float4*)(p + 16) = vB;
  };

  // merged DoG z-rings: D[i] accumulates (gl-part - gh-part); retire D[0].
  float D0[KH], D1[KH];
  #pragma unroll
  for (int i = 0; i < KH; ++i) { D0[i] = 0.f; D1[i] = 0.f; }

  // one plane of yconv + z-scatter + store; sh/sl bases passed statically.
  auto consumeQ = [&](int q, const float* __restrict__ sh, const float* __restrict__ sl) {
    float f[16], g[10];
    #pragma unroll
    for (int j = 0; j < 8; ++j) {                  // ds_read_b64: conflict-free
      float2 t = *(const float2*)&sh[hb + 2 * j];
      f[2 * j] = t.x; f[2 * j + 1] = t.y;
    }
    #pragma unroll
    for (int j = 0; j < 5; ++j) {
      float2 t = *(const float2*)&sl[lb + 2 * j];
      g[2 * j] = t.x; g[2 * j + 1] = t.y;
    }
    float ph0 = 0.f, ph1 = 0.f, pl0 = 0.f, pl1 = 0.f;
    #pragma unroll
    for (int j = 0; j < KH; ++j) {
      ph0 = fmaf(w.gh[j], f[j], ph0);
      ph1 = fmaf(w.gh[j], f[j + 1], ph1);
    }
    #pragma unroll
    for (int j = 0; j < KL; ++j) {
      pl0 = fmaf(w.gl[j], g[j], pl0);
      pl1 = fmaf(w.gl[j], g[j + 1], pl1);
    }
    #pragma unroll
    for (int i = 0; i < KH; ++i) {                 // -gh via free VOP3 neg modifier
      D0[i] = fmaf(-w.gh[KH - 1 - i], ph0, D0[i]);
      D1[i] = fmaf(-w.gh[KH - 1 - i], ph1, D1[i]);
    }
    #pragma unroll
    for (int i = 3; i < KL + 3; ++i) {
      D0[i] = fmaf(w.gl[KL + 2 - i], pl0, D0[i]);
      D1[i] = fmaf(w.gl[KL + 2 - i], pl1, D1[i]);
    }
    if (q >= 2 * RH) {
      float* op = obase + (size_t)(z0 + q - 2 * RH) * PLANE;
      op[0]    = D0[0];
      op[DIMS] = D1[0];
    }
    #pragma unroll
    for (int i = 0; i < KH - 1; ++i) { D0[i] = D0[i + 1]; D1[i] = D1[i + 1]; }
    D0[KH - 1] = 0.f; D1[KH - 1] = 0.f;
  };

  auto xconvP = [&](int cur, int slot) {
    const float* p = &sRaw[cur][slot][xr * SR + 4 * xq];
    float v[20];
    #pragma unroll
    for (int j = 0; j < 5; ++j) {                  // ds_read_b128: tiles 32 banks/phase
      float4 t = *(const float4*)(p + 4 * j);
      v[4 * j] = t.x; v[4 * j + 1] = t.y; v[4 * j + 2] = t.z; v[4 * j + 3] = t.w;
    }
    #pragma unroll
    for (int c = 0; c < 4; ++c) {                  // high, K=15
      float a = 0.f;
      #pragma unroll
      for (int k = 0; k < KH; ++k) a = fmaf(w.gh[k], v[c + 1 + k], a);
      sXh[cur][slot][(4 * xq + c) * SH + xr] = a;  // scalar write: exactly 2-way = free
    }
    if (xr >= 3 && xr <= 42) {
      #pragma unroll
      for (int c = 0; c < 4; ++c) {                // low, K=9
        float a = 0.f;
        #pragma unroll
        for (int k = 0; k < KL; ++k) a = fmaf(w.gl[k], v[c + 4 + k], a);
        sXl[cur][slot][(4 * xq + c) * SL + (xr - 3)] = a;
      }
    }
  };

  // prologue: planes 0,1 staged direct; planes 2,3 held in regs
  if (l_on) {
    loadP(0, a0, b0); loadP(1, a1, b1);
    stageP(0, 0, a0, b0); stageP(0, 1, a1, b1);
    loadP(2, a0, b0); loadP(3, a1, b1);
  }
  __syncthreads();                                 // B(0): sRaw[0] = planes 0,1

  for (int k = 0; k < NSEG; ++k) {                 // 23 segments, 2 planes each
    const int cur = k & 1;
    if (l_on) {
      if (2 * k + 2 < NSTEPS) {                    // stage planes 2k+2, 2k+3
        stageP(1 - cur, 0, a0, b0);
        stageP(1 - cur, 1, a1, b1);
      }
      if (2 * k + 4 < NSTEPS) {                    // issue planes 2k+4, 2k+5
        loadP(2 * k + 4, a0, b0);
        loadP(2 * k + 5, a1, b1);
      }
    }
    if (y_on && k >= 1) {                          // consume planes 2k-2, 2k-1
      consumeQ(2 * k - 2, &sXh[1 - cur][0][0], &sXl[1 - cur][0][0]);
      consumeQ(2 * k - 1, &sXh[1 - cur][1][0], &sXl[1 - cur][1][0]);
    }
    if (x_on) {                                    // planes 2k, 2k+1 -> sX[cur]
      xconvP(cur, 0);
      xconvP(cur, 1);
    }
    __syncthreads();                               // B(k+1)
  }
  if (y_on) {                                      // epilogue: planes 44,45 (sX[0], k=22)
    consumeQ(NSTEPS - 2, &sXh[0][0][0], &sXl[0][0][0]);
    consumeQ(NSTEPS - 1, &sXh[0][1][0], &sXl[0][1][0]);
  }
}

extern "C" void kernel_launch(void* const* d_in, const int* in_sizes, int n_in,
                              void* d_out, int out_size, void* d_ws, size_t ws_size,
                              hipStream_t stream) {
  const float* X = (const float*)d_in[0];
  float* out = (float*)d_out;

  DoGW w;
  {
    double s = 0.0;
    for (int i = 0; i < KL; ++i) {
      double t = i - (KL - 1) / 2.0;
      double g = exp(-(t * t) / (2.0 * 1.0 * 1.0));
      w.gl[i] = (float)g; s += g;
    }
    for (int i = 0; i < KL; ++i) w.gl[i] = (float)((double)w.gl[i] / s);
    s = 0.0;
    for (int i = 0; i < KH; ++i) {
      double t = i - (KH - 1) / 2.0;
      double g = exp(-(t * t) / (2.0 * 1.6 * 1.6));
      w.gh[i] = (float)g; s += g;
    }
    for (int i = 0; i < KH; ++i) w.gh[i] = (float)((double)w.gh[i] / s);
  }

  dog_v13<<<NBLK, 512, 0, stream>>>(X, out, w);
}

// Round 7
// 123.988 us; speedup vs baseline: 1.2572x; 1.0451x over previous
//
#include <hip/hip_runtime.h>
#include <math.h>

#define DIMS 160
#define PLANE (DIMS*DIMS)          // 25600
#define VOL (DIMS*PLANE)           // 4096000
#define NB 2
#define RH 7
#define RL 4
#define KH 15
#define KL 9

struct DoGW { float gl[KL]; float gh[KH]; };

// ============================ v14: two-pass design ============================
// Session evidence v7-v13: the persistent barrier-synced z-march is latency-
// bound (~3500 cyc wall per segment vs ~1100 cyc pipe demand; occupancy pinned
// 23-35% across ALL resource configs; halving barriers (v13) and removing LDS
// staging (v12) both failed to help). v14 abandons the structure:
//   Pass A dog_xy: per-plane 2D blur (x+y, both filters) -> ws. 8000 small
//     independent blocks, 2 barriers each, latency hidden by cross-block TLP.
//   Pass B dog_z: z-conv + DoG subtract. Pure register ring march, no LDS,
//     no barriers, perfectly coalesced; ws (65.5MB) is L3-resident.
// Numerics FMA-identical to v9. Fallback to v9 if ws_size < 65.5MB.

// ---- Pass A geometry ----
#define A_TS 32                    // output tile 32x32
#define A_RR 46                    // rows incl y-halo (32+14)
#define A_SRAW 48                  // raw row stride/width (x halo 8 each side)
// staging b128 at 48r+4q: per-8-lane phase starts {0,4,...,28}(+16r) -> tiles
// all 32 banks (verified per-phase). xconv b128 same geometry. yconv b64 at
// cx*50 / cx*42 (gcd(stride mod 32,32)=2): <=2-way = free (m136).
#define A_SH 50
#define A_SL 42

__global__ __launch_bounds__(256, 4)
void dog_xy(const float* __restrict__ X, float* __restrict__ wsH,
            float* __restrict__ wsL, DoGW w) {
  __shared__ __align__(16) float sRaw[A_RR * A_SRAW]; // 8832 B
  __shared__ __align__(16) float sHx[A_TS * A_SH];    // 6400 B
  __shared__ __align__(16) float sLx[A_TS * A_SL];    // 5376 B (20.6 KB)

  const int bid = blockIdx.x;
  const int xt = bid % 5, yt = (bid / 5) % 5, zp = bid / 25;  // zp = b*160+z
  const int x0 = xt * A_TS, y0 = yt * A_TS;
  const float* P = X + (size_t)zp * PLANE;
  const int tid = threadIdx.x;
  const bool xin = (xt > 0) && (xt < 4);

  // ---- stage raw 46x48 (x from x0-8, y clamped) : 552 float4 units ----
  #pragma unroll
  for (int rr = 0; rr < 3; ++rr) {
    const int u = tid + rr * 256;
    if (u < A_RR * 12) {
      const int row = u / 12, q = u % 12;
      const int yg = min(max(y0 + row - RH, 0), DIMS - 1);
      const float* rp = P + (size_t)yg * DIMS;
      const int gx = x0 - 8 + 4 * q;
      float4 v;
      if (xin || (gx >= 0 && gx + 4 <= DIMS)) {
        v = *(const float4*)(rp + gx);
      } else {
        v.x = rp[min(max(gx + 0, 0), DIMS - 1)];
        v.y = rp[min(max(gx + 1, 0), DIMS - 1)];
        v.z = rp[min(max(gx + 2, 0), DIMS - 1)];
        v.w = rp[min(max(gx + 3, 0), DIMS - 1)];
      }
      *(float4*)&sRaw[row * A_SRAW + 4 * q] = v;
    }
  }
  __syncthreads();

  // ---- xconv: 368 units (46 rows x 8 quads), 20-float window -> 4H (+4L) ----
  #pragma unroll
  for (int rr = 0; rr < 2; ++rr) {
    const int u = tid + rr * 256;
    if (u < A_RR * 8) {
      const int row = u >> 3, q = u & 7;
      const float* p = &sRaw[row * A_SRAW + 4 * q];
      float v[20];
      #pragma unroll
      for (int j = 0; j < 5; ++j) {
        float4 t = *(const float4*)(p + 4 * j);
        v[4*j] = t.x; v[4*j+1] = t.y; v[4*j+2] = t.z; v[4*j+3] = t.w;
      }
      #pragma unroll
      for (int c = 0; c < 4; ++c) {              // high, K=15
        float a = 0.f;
        #pragma unroll
        for (int k = 0; k < KH; ++k) a = fmaf(w.gh[k], v[c + 1 + k], a);
        sHx[(4 * q + c) * A_SH + row] = a;
      }
      if (row >= 3 && row <= 42) {
        #pragma unroll
        for (int c = 0; c < 4; ++c) {            // low, K=9
          float a = 0.f;
          #pragma unroll
          for (int k = 0; k < KL; ++k) a = fmaf(w.gl[k], v[c + 4 + k], a);
          sLx[(4 * q + c) * A_SL + (row - 3)] = a;
        }
      }
    }
  }
  __syncthreads();

  // ---- yconv + store: 512 units (32 cx x 16 y-pairs), b64 reads ----
  float* const oH = wsH + (size_t)zp * PLANE;
  float* const oL = wsL + (size_t)zp * PLANE;
  #pragma unroll
  for (int rr = 0; rr < 2; ++rr) {
    const int u = tid + rr * 256;
    const int cx = u & 31, cy0 = 2 * ((u >> 5) & 15);
    float f[16], g[10];
    #pragma unroll
    for (int j = 0; j < 8; ++j) {
      float2 t = *(const float2*)&sHx[cx * A_SH + cy0 + 2 * j];
      f[2*j] = t.x; f[2*j+1] = t.y;
    }
    #pragma unroll
    for (int j = 0; j < 5; ++j) {
      float2 t = *(const float2*)&sLx[cx * A_SL + cy0 + 2 * j];
      g[2*j] = t.x; g[2*j+1] = t.y;
    }
    float ph0 = 0.f, ph1 = 0.f, pl0 = 0.f, pl1 = 0.f;
    #pragma unroll
    for (int j = 0; j < KH; ++j) {
      ph0 = fmaf(w.gh[j], f[j], ph0);
      ph1 = fmaf(w.gh[j], f[j + 1], ph1);
    }
    #pragma unroll
    for (int j = 0; j < KL; ++j) {
      pl0 = fmaf(w.gl[j], g[j], pl0);
      pl1 = fmaf(w.gl[j], g[j + 1], pl1);
    }
    const int o = (y0 + cy0) * DIMS + x0 + cx;
    oH[o] = ph0; oH[o + DIMS] = ph1;
    oL[o] = pl0; oL[o + DIMS] = pl1;
  }
}

// ---- Pass B: z-ring march, no LDS/barriers, coalesced flat columns ----
#define B_CZ 40
#define B_NP (B_CZ + 2*RH)         // 54 planes marched per chunk

__global__ __launch_bounds__(256, 4)
void dog_z(const float* __restrict__ wsH, const float* __restrict__ wsL,
           float* __restrict__ out, DoGW w) {
  const int bid = blockIdx.x;
  const int cb = bid % 200, zc = bid / 200;
  const int col = cb * 256 + threadIdx.x;          // 0..51199 over (b,y,x)
  const int b = col / PLANE, rem = col % PLANE;    // rem = y*160+x (flat!)
  const int zb = zc * B_CZ;
  const float* __restrict__ pH = wsH + (size_t)b * VOL + rem;
  const float* __restrict__ pL = wsL + (size_t)b * VOL + rem;
  float* __restrict__ po = out + (size_t)b * VOL + rem;

  auto ldH = [&](int q) -> float {
    const int zs = min(max(zb - RH + q, 0), DIMS - 1);
    return pH[(size_t)zs * PLANE];
  };
  auto ldL = [&](int q) -> float {
    const int zs = min(max(zb - RH + q, 0), DIMS - 1);
    return pL[(size_t)zs * PLANE];
  };

  float D[KH];
  #pragma unroll
  for (int i = 0; i < KH; ++i) D[i] = 0.f;

  // depth-2 prefetch ping-pong (static regs; movs renamed by unroll-6)
  float hA = ldH(0), lA = ldL(0);
  float hB = ldH(1), lB = ldL(1);
  #pragma unroll 6
  for (int q = 0; q < B_NP; ++q) {
    float hC = 0.f, lC = 0.f;
    if (q + 2 < B_NP) { hC = ldH(q + 2); lC = ldL(q + 2); }
    #pragma unroll
    for (int i = 0; i < KH; ++i) D[i] = fmaf(-w.gh[KH - 1 - i], hA, D[i]);
    #pragma unroll
    for (int i = 3; i < KL + 3; ++i) D[i] = fmaf(w.gl[KL + 2 - i], lA, D[i]);
    if (q >= 2 * RH) po[(size_t)(zb + q - 2 * RH) * PLANE] = D[0];
    #pragma unroll
    for (int i = 0; i < KH - 1; ++i) D[i] = D[i + 1];
    D[KH - 1] = 0.f;
    hA = hB; lA = lB; hB = hC; lB = lC;
  }
}

// ============== fallback: v9 verbatim (session-best single kernel) ==============
#define TSX 16
#define TSY 32
#define NTX (DIMS/TSX)
#define NTY (DIMS/TSY)
#define CZ 32
#define NCH (DIMS/CZ)
#define NSTEPS (CZ + 2*RH)
#define YHR (TSY + 2*RH)
#define SR 48
#define SH 50
#define SL 42
#define RAWSZ (YHR*SR)
#define XHSZ (TSX*SH)
#define XLSZ (TSX*SL)
#define NBLK (NTX*NTY*NCH*NB)

__global__ __launch_bounds__(512, 4)
void dog_fb(const float* __restrict__ X, float* __restrict__ out, DoGW w) {
  __shared__ __align__(16) float sRaw[2][RAWSZ];
  __shared__ __align__(16) float sXh[2][XHSZ];
  __shared__ __align__(16) float sXl[2][XLSZ];

  const int bid = blockIdx.x;
  const int xt = bid % NTX;
  const int yt = (bid / NTX) % NTY;
  const int zc = (bid / (NTX * NTY)) % NCH;
  const int b  = bid / (NTX * NTY * NCH);
  const int x0 = xt * TSX, y0 = yt * TSY, z0 = zc * CZ;
  const float* Xb = X + (size_t)b * VOL;
  const int tid = threadIdx.x;
  const bool xfast = (x0 >= 8) && (x0 + 24 <= DIMS);

  const bool y_on = tid < 256;
  const int cx  = tid & 15;
  const int cy0 = 2 * ((tid >> 4) & 15);
  const int hb = cx * SH + cy0;
  const int lb = cx * SL + cy0;
  float* const obase = out + (size_t)b * VOL + (size_t)(y0 + cy0) * DIMS + (x0 + cx);

  const bool x_on = (tid >= 256) && (tid < 256 + YHR * 4);
  const int xu = tid - 256;
  const int xr = xu >> 2, xq = xu & 3;

  const bool l_on = tid >= (512 - YHR * 4);
  const int lu = tid - (512 - YHR * 4);
  const int lrow = lu >> 2, lt = lu & 3;
  const int lyg = min(max(y0 + lrow - RH, 0), DIMS - 1);
  const int lxb = x0 - 8 + 4 * lt;

  float4 vA, vB;
  auto loadP = [&](int s) {
    const int zsrc = min(max(z0 - RH + s, 0), DIMS - 1);
    const float* rowp = Xb + ((size_t)zsrc * DIMS + lyg) * DIMS;
    if (xfast) {
      vA = *(const float4*)(rowp + lxb);
      vB = *(const float4*)(rowp + lxb + 16);
    } else {
      vA.x = rowp[min(max(lxb + 0, 0), DIMS - 1)];
      vA.y = rowp[min(max(lxb + 1, 0), DIMS - 1)];
      vA.z = rowp[min(max(lxb + 2, 0), DIMS - 1)];
      vA.w = rowp[min(max(lxb + 3, 0), DIMS - 1)];
      vB.x = rowp[min(max(lxb + 16, 0), DIMS - 1)];
      vB.y = rowp[min(max(lxb + 17, 0), DIMS - 1)];
      vB.z = rowp[min(max(lxb + 18, 0), DIMS - 1)];
      vB.w = rowp[min(max(lxb + 19, 0), DIMS - 1)];
    }
  };
  auto stageP = [&](int buf) {
    float* p = &sRaw[buf][lrow * SR + 4 * lt];
    *(float4*)(p) = vA;
    *(float4*)(p + 16) = vB;
  };

  float D0[KH], D1[KH];
  #pragma unroll
  for (int i = 0; i < KH; ++i) { D0[i] = 0.f; D1[i] = 0.f; }

  auto consumeQ = [&](int q) {
    const int qb = q & 1;
    float f[16], g[10];
    #pragma unroll
    for (int j = 0; j < 8; ++j) {
      float2 t = *(const float2*)&sXh[qb][hb + 2 * j];
      f[2 * j] = t.x; f[2 * j + 1] = t.y;
    }
    #pragma unroll
    for (int j = 0; j < 5; ++j) {
      float2 t = *(const float2*)&sXl[qb][lb + 2 * j];
      g[2 * j] = t.x; g[2 * j + 1] = t.y;
    }
    float ph0 = 0.f, ph1 = 0.f, pl0 = 0.f, pl1 = 0.f;
    #pragma unroll
    for (int j = 0; j < KH; ++j) {
      ph0 = fmaf(w.gh[j], f[j], ph0);
      ph1 = fmaf(w.gh[j], f[j + 1], ph1);
    }
    #pragma unroll
    for (int j = 0; j < KL; ++j) {
      pl0 = fmaf(w.gl[j], g[j], pl0);
      pl1 = fmaf(w.gl[j], g[j + 1], pl1);
    }
    #pragma unroll
    for (int i = 0; i < KH; ++i) {
      D0[i] = fmaf(-w.gh[KH - 1 - i], ph0, D0[i]);
      D1[i] = fmaf(-w.gh[KH - 1 - i], ph1, D1[i]);
    }
    #pragma unroll
    for (int i = 3; i < KL + 3; ++i) {
      D0[i] = fmaf(w.gl[KL + 2 - i], pl0, D0[i]);
      D1[i] = fmaf(w.gl[KL + 2 - i], pl1, D1[i]);
    }
    if (q >= 2 * RH) {
      float* op = obase + (size_t)(z0 + q - 2 * RH) * PLANE;
      op[0]    = D0[0];
      op[DIMS] = D1[0];
    }
    #pragma unroll
    for (int i = 0; i < KH - 1; ++i) { D0[i] = D0[i + 1]; D1[i] = D1[i + 1]; }
    D0[KH - 1] = 0.f; D1[KH - 1] = 0.f;
  };

  auto xconvP = [&](int cur) {
    const float* p = &sRaw[cur][xr * SR + 4 * xq];
    float v[20];
    #pragma unroll
    for (int j = 0; j < 5; ++j) {
      float4 t = *(const float4*)(p + 4 * j);
      v[4 * j] = t.x; v[4 * j + 1] = t.y; v[4 * j + 2] = t.z; v[4 * j + 3] = t.w;
    }
    #pragma unroll
    for (int c = 0; c < 4; ++c) {
      float a = 0.f;
      #pragma unroll
      for (int k = 0; k < KH; ++k) a = fmaf(w.gh[k], v[c + 1 + k], a);
      sXh[cur][(4 * xq + c) * SH + xr] = a;
    }
    if (xr >= 3 && xr <= 42) {
      #pragma unroll
      for (int c = 0; c < 4; ++c) {
        float a = 0.f;
        #pragma unroll
        for (int k = 0; k < KL; ++k) a = fmaf(w.gl[k], v[c + 4 + k], a);
        sXl[cur][(4 * xq + c) * SL + (xr - 3)] = a;
      }
    }
  };

  if (l_on) { loadP(0); stageP(0); loadP(1); }
  __syncthreads();

  #pragma unroll 5
  for (int s = 0; s < NSTEPS; ++s) {
    const int cur = s & 1;
    if (l_on) {
      if (s + 1 < NSTEPS) stageP(1 - cur);
      if (s + 2 < NSTEPS) loadP(s + 2);
    }
    if (y_on && s >= 1) consumeQ(s - 1);
    if (x_on) xconvP(cur);
    __syncthreads();
  }
  if (y_on) consumeQ(NSTEPS - 1);
}

extern "C" void kernel_launch(void* const* d_in, const int* in_sizes, int n_in,
                              void* d_out, int out_size, void* d_ws, size_t ws_size,
                              hipStream_t stream) {
  const float* X = (const float*)d_in[0];
  float* out = (float*)d_out;

  DoGW w;
  {
    double s = 0.0;
    for (int i = 0; i < KL; ++i) {
      double t = i - (KL - 1) / 2.0;
      double g = exp(-(t * t) / (2.0 * 1.0 * 1.0));
      w.gl[i] = (float)g; s += g;
    }
    for (int i = 0; i < KL; ++i) w.gl[i] = (float)((double)w.gl[i] / s);
    s = 0.0;
    for (int i = 0; i < KH; ++i) {
      double t = i - (KH - 1) / 2.0;
      double g = exp(-(t * t) / (2.0 * 1.6 * 1.6));
      w.gh[i] = (float)g; s += g;
    }
    for (int i = 0; i < KH; ++i) w.gh[i] = (float)((double)w.gh[i] / s);
  }

  const size_t need = 2ull * NB * VOL * sizeof(float);   // 65,536,000 B
  if (ws_size >= need) {
    float* wsH = (float*)d_ws;
    float* wsL = wsH + (size_t)NB * VOL;
    dog_xy<<<NB * DIMS * 25, 256, 0, stream>>>(X, wsH, wsL, w);
    dog_z<<<(NB * PLANE / 256) * (DIMS / B_CZ), 256, 0, stream>>>(wsH, wsL, out, w);
  } else {
    dog_fb<<<NBLK, 512, 0, stream>>>(X, out, w);
  }
}